// Round 14
// baseline (113.988 us; speedup 1.0000x reference)
//
#include <hip/hip_runtime.h>
#include <hip/hip_bf16.h>
#include <cmath>

#define T_DIM 2048
#define B_DIM 16
#define D_DIM 256
#define BD (B_DIM * D_DIM)
#define BM 128
#define BN 32                  // s-rows per stage (16KB bf16 in LDS)
#define NEG_INF_F (-1e30f)
#define SCALE_LOG2 14.4269504088896f  // 10 / ln(2)
#define LN2F 0.6931471805599453f

typedef __attribute__((ext_vector_type(8))) short bf16x8;
typedef __attribute__((ext_vector_type(4))) float f32x4;

static __device__ __forceinline__ ushort f2bf(float f) {
    union { float f; unsigned int u; } x; x.f = f;
    unsigned int r = (x.u + 0x7FFFu + ((x.u >> 16) & 1u)) >> 16;  // RNE
    return (ushort)r;
}

// ---- Phase A: REG-STAGED (no global_load_lds, no pre-convert pass) ----
// Loads go to VGPRs (pipelined misses, m135) and are converted f32->bf16 in
// register during the ds_write. Stage n+1's loads are issued BEFORE stage n's
// compute, so their latency hides under MFMA+LSE (T14).
__global__ __launch_bounds__(256) void partial_lse_rs_kernel(
    const float* __restrict__ q1, const float* __restrict__ k2,
    const float* __restrict__ q2, const float* __restrict__ k1,
    const int* __restrict__ len_q1, const int* __restrict__ len_k2,
    const int* __restrict__ len_q2, const int* __restrict__ len_k1,
    float2* __restrict__ partial, float* __restrict__ diag,
    int chunk, int ns)
{
    const int pair = blockIdx.z / ns;
    const int sc   = blockIdx.z % ns;
    const int b    = blockIdx.y;
    const int t0   = blockIdx.x * BM;

    const float* pred = (pair == 0) ? q1 : q2;
    const float* targ = (pair == 0) ? k2 : k1;
    const int lp = (pair == 0) ? len_q1[b] : len_q2[b];
    const int lt = (pair == 0) ? len_k2[b] : len_k1[b];
    const int m  = min(lp, lt);
    const int s_start = sc * chunk;
    if (t0 >= m || s_start >= m) return;   // block-uniform early exit
    const int s_hi = min(m, s_start + chunk);
    const int pb = pair * B_DIM + b;

    __shared__ ushort tl[2][BN * 256];   // 2 x 16KB double buffer

    const int tid = threadIdx.x;
    const int w   = tid >> 6;
    const int l   = tid & 63;
    const int c   = l & 15;
    const int g   = l >> 4;

    float4 rg[8];   // staging registers: 8 rows x (lane's 4 floats)

    // wave w owns stage rows [8w, 8w+8); lane l covers cols [4l, 4l+4)
#define LOADSTAGE(s0_) do {                                                   \
        _Pragma("unroll")                                                     \
        for (int q = 0; q < 8; ++q)                                           \
            rg[q] = *reinterpret_cast<const float4*>(                         \
                &targ[(size_t)((s0_) + 8 * w + q) * BD + (size_t)b * D_DIM + l * 4]); \
    } while (0)

#define WRITESTAGE(bufp_) do {                                                \
        _Pragma("unroll")                                                     \
        for (int q = 0; q < 8; ++q) {                                         \
            const int r_ = 8 * w + q;                                         \
            ushort4 h_;                                                       \
            h_.x = f2bf(rg[q].x); h_.y = f2bf(rg[q].y);                       \
            h_.z = f2bf(rg[q].z); h_.w = f2bf(rg[q].w);                       \
            *reinterpret_cast<ushort4*>(                                      \
                &(bufp_)[(r_ << 8) + ((l * 4) ^ ((r_ & 15) << 3))]) = h_;     \
        }                                                                     \
    } while (0)

    // ---- issue stage-0 loads first (longest latency chain)
    LOADSTAGE(s_start);

    // ---- afrag: direct f32 gathers, scale folded (prologue-only)
    bf16x8 afrag[2][8];
    #pragma unroll
    for (int i = 0; i < 2; ++i) {
        const float* base = &pred[(size_t)(t0 + 32 * w + 16 * i + c) * BD
                                  + (size_t)b * D_DIM + g * 8];
        #pragma unroll
        for (int kk = 0; kk < 8; ++kk) {
            const float4 v0 = *reinterpret_cast<const float4*>(base + kk * 32);
            const float4 v1 = *reinterpret_cast<const float4*>(base + kk * 32 + 4);
            bf16x8 av;
            av[0] = (short)f2bf(v0.x * SCALE_LOG2); av[1] = (short)f2bf(v0.y * SCALE_LOG2);
            av[2] = (short)f2bf(v0.z * SCALE_LOG2); av[3] = (short)f2bf(v0.w * SCALE_LOG2);
            av[4] = (short)f2bf(v1.x * SCALE_LOG2); av[5] = (short)f2bf(v1.y * SCALE_LOG2);
            av[6] = (short)f2bf(v1.z * SCALE_LOG2); av[7] = (short)f2bf(v1.w * SCALE_LOG2);
            afrag[i][kk] = av;
        }
    }

    WRITESTAGE(tl[0]);   // compiler waits vmcnt for rg, then LDS writes

    float tmax[2][4], tsum[2][4], dg[2][4];
    #pragma unroll
    for (int i = 0; i < 2; ++i)
        #pragma unroll
        for (int rr = 0; rr < 4; ++rr) {
            tmax[i][rr] = NEG_INF_F; tsum[i][rr] = 0.0f; dg[i][rr] = NEG_INF_F;
        }

    __syncthreads();
    int cur = 0;

    for (int s0 = s_start; s0 < s_hi; s0 += BN) {
        const bool pf = (s0 + BN < s_hi);
        if (pf) LOADSTAGE(s0 + BN);   // pipelined misses in flight during compute

        f32x4 acc[2][2];
        #pragma unroll
        for (int i = 0; i < 2; ++i)
            #pragma unroll
            for (int j = 0; j < 2; ++j)
                acc[i][j] = (f32x4){0.f, 0.f, 0.f, 0.f};

        const ushort* buf = tl[cur];
        #pragma unroll
        for (int kk = 0; kk < 8; ++kk) {
            bf16x8 bfrag[2];
            #pragma unroll
            for (int j = 0; j < 2; ++j) {
                const int r = 16 * j + c;
                const int d = g * 8 + kk * 32;
                bfrag[j] = *reinterpret_cast<const bf16x8*>(&buf[(r << 8) + (d ^ (c << 3))]);
            }
            #pragma unroll
            for (int i = 0; i < 2; ++i)
                #pragma unroll
                for (int j = 0; j < 2; ++j)
                    acc[i][j] = __builtin_amdgcn_mfma_f32_16x16x32_bf16(
                        afrag[i][kk], bfrag[j], acc[i][j], 0, 0, 0);
        }

        // ---- thread-local online LSE (log2 domain, 2 cols/row/stage)
        #pragma unroll
        for (int i = 0; i < 2; ++i) {
            #pragma unroll
            for (int rr = 0; rr < 4; ++rr) {
                const int trow = t0 + 32 * w + 16 * i + 4 * g + rr;
                const int s0c  = s0 + c;
                float v0 = (s0c      < m) ? acc[i][0][rr] : NEG_INF_F;
                float v1 = (s0c + 16 < m) ? acc[i][1][rr] : NEG_INF_F;
                if (s0c      == trow) dg[i][rr] = v0;
                if (s0c + 16 == trow) dg[i][rr] = v1;
                const float cmax = fmaxf(v0, v1);
                const float nmax = fmaxf(tmax[i][rr], cmax);
                const float add  = exp2f(v0 - nmax) + exp2f(v1 - nmax);
                tsum[i][rr] = tsum[i][rr] * exp2f(tmax[i][rr] - nmax) + add;
                tmax[i][rr] = nmax;
            }
        }

        if (pf) WRITESTAGE(tl[cur ^ 1]);   // regs arrived during compute
        __syncthreads();
        cur ^= 1;
    }
#undef LOADSTAGE
#undef WRITESTAGE

    // ---- 16-lane LSE merge + writes (once per block)
    const bool own_diag = (t0 >= s_start) && (t0 + BM <= s_start + chunk);
    #pragma unroll
    for (int i = 0; i < 2; ++i) {
        #pragma unroll
        for (int rr = 0; rr < 4; ++rr) {
            float M = tmax[i][rr], S = tsum[i][rr];
            #pragma unroll
            for (int msk = 1; msk < 16; msk <<= 1) {
                const float Mo = __shfl_xor(M, msk, 64);
                const float So = __shfl_xor(S, msk, 64);
                const float nM = fmaxf(M, Mo);
                S = S * exp2f(M - nM) + So * exp2f(Mo - nM);
                M = nM;
            }
            float d = dg[i][rr];
            #pragma unroll
            for (int msk = 1; msk < 16; msk <<= 1)
                d = fmaxf(d, __shfl_xor(d, msk, 64));
            if (c == 0) {
                const int trow = t0 + 32 * w + 16 * i + 4 * g + rr;
                partial[((size_t)(pb << 11) + trow) * ns + sc] = make_float2(M, S);
                if (own_diag) diag[(pb << 11) + trow] = d;
            }
        }
    }
}

// ---- Phase B: merge partial LSEs (log2 domain) ----
__global__ __launch_bounds__(256) void combine_kernel(
    const int* __restrict__ len_q1, const int* __restrict__ len_k2,
    const int* __restrict__ len_q2, const int* __restrict__ len_k1,
    const float2* __restrict__ partial, const float* __restrict__ diag,
    float* __restrict__ per_sample, int chunk, int stride)
{
    const int pb   = blockIdx.x;
    const int pair = pb >> 4;
    const int b    = pb & 15;
    const int lp = (pair == 0) ? len_q1[b] : len_q2[b];
    const int lt = (pair == 0) ? len_k2[b] : len_k1[b];
    const int m  = min(lp, lt);

    float local = 0.0f;
    if (m > 0) {
        const int nch = (m + chunk - 1) / chunk;
        for (int t = threadIdx.x; t < m; t += 256) {
            float M = NEG_INF_F, S = 0.0f;
            for (int e = 0; e < nch; ++e) {
                const float2 p = partial[((size_t)(pb << 11) + t) * stride + e];
                const float nM = fmaxf(M, p.x);
                S = S * exp2f(M - nM) + p.y * exp2f(p.x - nM);
                M = nM;
            }
            local += LN2F * ((__log2f(S) + M) - diag[(pb << 11) + t]);
        }
    }

    __shared__ float ws4[4];
    #pragma unroll
    for (int msk = 1; msk < 64; msk <<= 1)
        local += __shfl_xor(local, msk, 64);
    if ((threadIdx.x & 63) == 0) ws4[threadIdx.x >> 6] = local;
    __syncthreads();
    if (threadIdx.x == 0) {
        const float tot = ws4[0] + ws4[1] + ws4[2] + ws4[3];
        per_sample[pb] = (m > 0) ? (tot / (float)m) : 0.0f;
    }
}

__global__ void finalize_kernel(
    const int* __restrict__ len_q1, const int* __restrict__ len_k2,
    const int* __restrict__ len_q2, const int* __restrict__ len_k1,
    const float* __restrict__ per_sample, float* __restrict__ out)
{
    if (threadIdx.x != 0 || blockIdx.x != 0) return;
    float losses[2];
    #pragma unroll
    for (int p = 0; p < 2; ++p) {
        float tot = 0.0f, nv = 0.0f;
        for (int b = 0; b < B_DIM; ++b) {
            const int lp = (p == 0) ? len_q1[b] : len_q2[b];
            const int lt = (p == 0) ? len_k2[b] : len_k1[b];
            const int mm = min(lp, lt);
            if (mm > 0) { tot += per_sample[p * B_DIM + b]; nv += 1.0f; }
        }
        losses[p] = (nv > 0.0f) ? (tot / nv) : 0.0f;
    }
    out[0] = 0.5f * (losses[0] + losses[1]);
}

extern "C" void kernel_launch(void* const* d_in, const int* in_sizes, int n_in,
                              void* d_out, int out_size, void* d_ws, size_t ws_size,
                              hipStream_t stream) {
    const float* q1 = (const float*)d_in[0];
    const float* k2 = (const float*)d_in[1];
    const float* q2 = (const float*)d_in[2];
    const float* k1 = (const float*)d_in[3];
    const int* lq1 = (const int*)d_in[6];
    const int* lk2 = (const int*)d_in[7];
    const int* lq2 = (const int*)d_in[8];
    const int* lk1 = (const int*)d_in[9];
    float* out = (float*)d_out;

    const size_t rows = (size_t)2 * B_DIM * T_DIM;   // 65536

    int ns = 8;                                      // chunk = 256
    while (ns > 1) {
        const size_t need = rows * ns * sizeof(float2) + rows * sizeof(float) + 256;
        if (need <= ws_size) break;
        ns >>= 1;
    }
    const int chunk = T_DIM / ns;

    float2* partial    = (float2*)d_ws;
    float*  diag       = (float*)((char*)d_ws + rows * ns * sizeof(float2));
    float*  per_sample = diag + rows;

    dim3 gridA(T_DIM / BM, B_DIM, 2 * ns);   // 16 x 16 x 16
    partial_lse_rs_kernel<<<gridA, 256, 0, stream>>>(
        q1, k2, q2, k1, lq1, lk2, lq2, lk1, partial, diag, chunk, ns);

    combine_kernel<<<32, 256, 0, stream>>>(
        lq1, lk2, lq2, lk1, partial, diag, per_sample, chunk, ns);

    finalize_kernel<<<1, 64, 0, stream>>>(lq1, lk2, lq2, lk1, per_sample, out);
}